// Round 1
// baseline (2283.428 us; speedup 1.0000x reference)
//
#include <hip/hip_runtime.h>
#include <math.h>

#define BN 8192
#define ENC 256
#define NCL 32
#define BROWS 4
#define SMEM_BYTES (BROWS * BN * 4 + BROWS * NCL * 4)

// ---------------- K1: per-row sumsq, argmax/max of categorical ----------------
__global__ void prep_kernel(const float* __restrict__ enc, const float* __restrict__ cat,
                            float* __restrict__ sq, float* __restrict__ maxg,
                            int* __restrict__ hard) {
    int w = threadIdx.x >> 6, l = threadIdx.x & 63;
    int row = blockIdx.x * 4 + w;
    const float4* e4 = (const float4*)(enc + (size_t)row * ENC);
    float4 v = e4[l];  // 64 lanes x float4 = 256 floats
    float s = v.x * v.x + v.y * v.y + v.z * v.z + v.w * v.w;
    for (int m = 32; m; m >>= 1) s += __shfl_xor(s, m, 64);

    float cv = (l < NCL) ? cat[(size_t)row * NCL + l] : -__builtin_huge_valf();
    int ci = (l < NCL) ? l : 0x7fffffff;
    for (int m = 32; m; m >>= 1) {
        float ov = __shfl_xor(cv, m, 64);
        int oi = __shfl_xor(ci, m, 64);
        if (ov > cv || (ov == cv && oi < ci)) { cv = ov; ci = oi; }
    }
    if (l == 0) { sq[row] = s; maxg[row] = cv; hard[row] = ci; }
}

// ---------------- K2: fused cdist + exact rank-26 select + counts + entropy ----------------
__global__ __launch_bounds__(256, 1)
void overlap_kernel(const float* __restrict__ enc, const float* __restrict__ sq,
                    const float* __restrict__ maxg, const int* __restrict__ hard,
                    const int* __restrict__ kptr, float* __restrict__ out) {
    extern __shared__ float smem[];
    float* sdist = smem;                       // BROWS * 8192 floats
    int* sbins = (int*)(smem + BROWS * BN);    // BROWS * 32 ints

    int t = threadIdx.x, w = t >> 6, l = t & 63;
    int i0 = blockIdx.x * BROWS;
    if (t < BROWS * NCL) sbins[t] = 0;

    const float4* enc4 = (const float4*)enc;
    const float4* ei4 = enc4 + (size_t)i0 * (ENC / 4);  // block-uniform -> scalar loads
    float sqi0 = sq[i0], sqi1 = sq[i0 + 1], sqi2 = sq[i0 + 2], sqi3 = sq[i0 + 3];

    // Phase 1: distances for rows i0..i0+3 vs all j, into LDS (as sqrt'd dist, like ref)
    for (int q = 0; q < 32; ++q) {
        int j = q * 256 + t;
        const float4* rj = enc4 + (size_t)j * (ENC / 4);
        float a0 = 0.f, a1 = 0.f, a2 = 0.f, a3 = 0.f;
#pragma unroll 4
        for (int cc = 0; cc < ENC / 4; ++cc) {
            float4 vv = rj[cc];
            float4 e0 = ei4[cc];
            float4 e1 = ei4[64 + cc];
            float4 e2 = ei4[128 + cc];
            float4 e3 = ei4[192 + cc];
            a0 = fmaf(vv.x, e0.x, a0); a0 = fmaf(vv.y, e0.y, a0);
            a0 = fmaf(vv.z, e0.z, a0); a0 = fmaf(vv.w, e0.w, a0);
            a1 = fmaf(vv.x, e1.x, a1); a1 = fmaf(vv.y, e1.y, a1);
            a1 = fmaf(vv.z, e1.z, a1); a1 = fmaf(vv.w, e1.w, a1);
            a2 = fmaf(vv.x, e2.x, a2); a2 = fmaf(vv.y, e2.y, a2);
            a2 = fmaf(vv.z, e2.z, a2); a2 = fmaf(vv.w, e2.w, a2);
            a3 = fmaf(vv.x, e3.x, a3); a3 = fmaf(vv.y, e3.y, a3);
            a3 = fmaf(vv.z, e3.z, a3); a3 = fmaf(vv.w, e3.w, a3);
        }
        float sqj = sq[j];
        sdist[0 * BN + j] = sqrtf(fmaxf(sqi0 + sqj - 2.0f * a0, 0.0f));
        sdist[1 * BN + j] = sqrtf(fmaxf(sqi1 + sqj - 2.0f * a1, 0.0f));
        sdist[2 * BN + j] = sqrtf(fmaxf(sqi2 + sqj - 2.0f * a2, 0.0f));
        sdist[3 * BN + j] = sqrtf(fmaxf(sqi3 + sqj - 2.0f * a3, 0.0f));
    }
    __syncthreads();

    // Phase 2: wave w owns row w. Load row into registers as uint bit patterns.
    // dist >= 0 so uint compare == float compare (monotone), strict-< mirrors ref exactly.
    unsigned u[128];
    const float4* sd4 = (const float4*)(sdist + (size_t)w * BN);
#pragma unroll
    for (int e4i = 0; e4i < 32; ++e4i) {
        float4 v = sd4[e4i * 64 + l];
        u[e4i * 4 + 0] = __float_as_uint(v.x);
        u[e4i * 4 + 1] = __float_as_uint(v.y);
        u[e4i * 4 + 2] = __float_as_uint(v.z);
        u[e4i * 4 + 3] = __float_as_uint(v.w);
    }

    int topn = *kptr + 1;  // 26: thr = sorted[k] = 26th smallest
    unsigned lo = 0u, hi = 0x7F800000u;  // [0, +inf]
    while (lo < hi) {
        unsigned mid = lo + ((hi - lo) >> 1);
        int cnt = 0;
#pragma unroll
        for (int e = 0; e < 128; ++e) cnt += (u[e] <= mid) ? 1 : 0;
        for (int m = 32; m; m >>= 1) cnt += __shfl_xor(cnt, m, 64);
        if (cnt >= topn) hi = mid; else lo = mid + 1;
    }
    unsigned thrb = lo;  // bit pattern of sorted[25]

    // Phase 3: strict < thr, per-cluster counts (rare hits -> LDS atomics)
#pragma unroll
    for (int e4i = 0; e4i < 32; ++e4i) {
#pragma unroll
        for (int c = 0; c < 4; ++c) {
            if (u[e4i * 4 + c] < thrb) {
                int j = e4i * 256 + l * 4 + c;
                atomicAdd(&sbins[w * NCL + hard[j]], 1);
            }
        }
    }
    __syncthreads();

    // Phase 4: entropy epilogue, lanes 0..31 = clusters
    if (l < NCL) {
        int cnt = sbins[w * NCL + l];
        int n = cnt;
        for (int m = 16; m; m >>= 1) n += __shfl_xor(n, m, 64);
        float nf = (float)n;
        float b = (float)cnt / nf;
        float term = -b * logf(b + 1e-5f);
        for (int m = 16; m; m >>= 1) term += __shfl_xor(term, m, 64);
        if (l == 0) out[i0 + w] = term * maxg[i0 + w];
    }
}

extern "C" void kernel_launch(void* const* d_in, const int* in_sizes, int n_in,
                              void* d_out, int out_size, void* d_ws, size_t ws_size,
                              hipStream_t stream) {
    const float* enc = (const float*)d_in[0];
    const float* cat = (const float*)d_in[1];
    const int* kptr = (const int*)d_in[2];
    float* out = (float*)d_out;

    float* sq = (float*)d_ws;
    float* maxg = sq + BN;
    int* hard = (int*)(maxg + BN);

    (void)hipFuncSetAttribute((const void*)overlap_kernel,
                              hipFuncAttributeMaxDynamicSharedMemorySize, SMEM_BYTES);

    prep_kernel<<<BN / 4, 256, 0, stream>>>(enc, cat, sq, maxg, hard);
    overlap_kernel<<<BN / BROWS, 256, SMEM_BYTES, stream>>>(enc, sq, maxg, hard, kptr, out);
}